// Round 5
// baseline (112.129 us; speedup 1.0000x reference)
//
#include <hip/hip_runtime.h>
#include <hip/hip_bf16.h>

#define NB 16
#define NP 1024
#define NS 32
#define NC 76
#define XSTR 104    // x buffer k-stride (shorts): 96 used + 8 pad
#define HSTR2 136   // h1 buffer k-stride (shorts): 128 used + 8 pad
#define TPB 4       // tiles per block; tile = 2 points = 64 MFMA cols

typedef __attribute__((ext_vector_type(8))) short bf16x8;
typedef __attribute__((ext_vector_type(4))) float f32x4;

__device__ inline short f2bf(float f) {
  unsigned u = __builtin_bit_cast(unsigned, f);
  u = u + 0x7fffu + ((u >> 16) & 1u);   // RNE
  return (short)(u >> 16);
}
// packed f32x2 -> bf16x2 (1 VALU op for 2 values), RNE on gfx950
__device__ inline unsigned cvt_pk_bf16(float lo, float hi) {
  unsigned r;
  asm("v_cvt_pk_bf16_f32 %0, %1, %2" : "=v"(r) : "v"(lo), "v"(hi));
  return r;
}
// swizzles: fold col bit5 (bank-dead: 32*stride = 0 mod 32 words) into the
// 8-short (16B) block bit. Bijective per col; applied on EVERY access.
__device__ inline int swzx(int col, int k) {
  return (col * XSTR + k) ^ ((((col) >> 5) & 1) << 3);
}
__device__ inline int swzh(int col, int k) {
  return (col * HSTR2 + k) ^ ((((col) >> 5) & 1) << 3);
}
// max across the 16-lane row dimension via DPP butterfly (no LDS)
__device__ inline float dpp_max16(float v) {
  int x;
  x = __builtin_amdgcn_update_dpp(0, __builtin_bit_cast(int, v), 0xB1, 0xf, 0xf, true);
  v = fmaxf(v, __builtin_bit_cast(float, x));
  x = __builtin_amdgcn_update_dpp(0, __builtin_bit_cast(int, v), 0x4E, 0xf, 0xf, true);
  v = fmaxf(v, __builtin_bit_cast(float, x));
  x = __builtin_amdgcn_update_dpp(0, __builtin_bit_cast(int, v), 0x141, 0xf, 0xf, true);
  v = fmaxf(v, __builtin_bit_cast(float, x));
  x = __builtin_amdgcn_update_dpp(0, __builtin_bit_cast(int, v), 0x140, 0xf, 0xf, true);
  v = fmaxf(v, __builtin_bit_cast(float, x));
  return v;
}

// ---------------- kernel 1: per-(b,p) frames ----------------
__global__ void frames_kernel(const float* __restrict__ inp,
                              const float* __restrict__ normal,
                              float* __restrict__ out, float* __restrict__ ws) {
  const int bp = blockIdx.x * 256 + threadIdx.x;   // 0..16383
  const int b = bp >> 10, p = bp & 1023;

  float azi[3];
#pragma unroll
  for (int i = 0; i < 3; ++i) {
    const float* row = inp + (size_t)((b*NC + 6 + i)*NP + p) * NS;
    float s = 0.f;
#pragma unroll
    for (int q = 0; q < 8; ++q) {
      float4 v = ((const float4*)row)[q];
      s += (v.x + v.y) + (v.z + v.w);
    }
    s -= row[0];                  // mean over s=1..31
    azi[i] = s / 31.f;
  }
  float nr[3];
#pragma unroll
  for (int i = 0; i < 3; ++i) nr[i] = normal[(size_t)(b*NP + p)*3 + i];
  float nn = sqrtf(nr[0]*nr[0] + nr[1]*nr[1] + nr[2]*nr[2]) + 1e-8f;
  nr[0] /= nn; nr[1] /= nn; nr[2] /= nn;
  float au[3] = {azi[0], azi[1], azi[2]};
  float an = sqrtf(au[0]*au[0] + au[1]*au[1] + au[2]*au[2]) + 1e-8f;
  au[0] /= an; au[1] /= an; au[2] /= an;
  float d = au[0]*nr[0] + au[1]*nr[1] + au[2]*nr[2];
  float xax[3] = {au[0] - d*nr[0], au[1] - d*nr[1], au[2] - d*nr[2]};
  float xn = sqrtf(xax[0]*xax[0] + xax[1]*xax[1] + xax[2]*xax[2]) + 1e-8f;
  xax[0] /= xn; xax[1] /= xn; xax[2] /= xn;
  float yax[3] = {nr[1]*xax[2] - nr[2]*xax[1],
                  nr[2]*xax[0] - nr[0]*xax[2],
                  nr[0]*xax[1] - nr[1]*xax[0]};
#pragma unroll
  for (int i = 0; i < 3; ++i)
    out[(size_t)(b*131 + i)*NP + p] = au[i];      // azi_u -> out ch 0..2

  float* w = ws + (size_t)bp * 12;                // R rows + R*azi_u
  w[0]=xax[0]; w[1]=xax[1]; w[2]=xax[2];
  w[3]=yax[0]; w[4]=yax[1]; w[5]=yax[2];
  w[6]=nr[0];  w[7]=nr[1];  w[8]=nr[2];
  w[9]  = xax[0]*au[0] + xax[1]*au[1] + xax[2]*au[2];
  w[10] = yax[0]*au[0] + yax[1]*au[1] + yax[2]*au[2];
  w[11] = nr[0]*au[0]  + nr[1]*au[1]  + nr[2]*au[2];
}

// ---------------- kernel 2: fused MLP + pool ----------------
// 256 threads = 4 waves; wave wv owns output rows 32*wv..32*wv+31 (mf=0,1).
// Tile = 2 points = 64 cols. x and h1 in SEPARATE LDS buffers -> 2 barriers
// per tile; x(t+1) fill overlaps L2(t) compute.
// x layout [col=(lp2,s)][k]: k 0..63 feats (ch12..75); 64..66 rel; 67..69 o_n;
// 70..72 dir_dif; 73..95 zero (w1 frags zero there too).
__global__ __launch_bounds__(256, 3)
void mlp_kernel(const float* __restrict__ inp, const float* __restrict__ w1g,
                const float* __restrict__ b1g, const float* __restrict__ w2g,
                const float* __restrict__ b2g, const float* __restrict__ ws,
                float* __restrict__ out) {
  __shared__ short xb[64 * XSTR];    // 13,312 B
  __shared__ short hb[64 * HSTR2];   // 17,408 B
  const int tid = threadIdx.x;
  const int lane = tid & 63;
  const int wv = tid >> 6;          // wave 0..3 -> rows 32*wv..
  const int l15 = lane & 15;
  const int l4 = lane >> 4;         // 0..3

  const int tile0 = blockIdx.x * TPB;

  // feat-fill map: per j, bank starts = 16(s4&1) ^ lp2*4 + 2chq -> all distinct
  const int s4  = tid & 7;          // s quad
  const int chq = (tid >> 3) & 15;  // channel quad -> k = 4*chq
  const int lp2 = tid >> 7;         // point in tile
  const int colb = lp2*32 + 4*s4;

  // ----- per-wave weight fragments (rows 32*wv+16*mf+l15) -----
  bf16x8 w1f[2][3];
#pragma unroll
  for (int mf = 0; mf < 2; ++mf)
#pragma unroll
    for (int ks = 0; ks < 3; ++ks) {
      bf16x8 a;
#pragma unroll
      for (int j = 0; j < 8; ++j) {
        int row = 32*wv + 16*mf + l15;
        int kk = 32*ks + 8*l4 + j;
        float v = 0.f;
        if (kk < 73) {
          int c = (kk < 64) ? (kk + 3) : ((kk < 67) ? (kk - 64) : kk);
          v = w1g[row*73 + c];
        }
        a[j] = f2bf(v);
      }
      w1f[mf][ks] = a;
    }
  bf16x8 w2f[2][4];
#pragma unroll
  for (int mf = 0; mf < 2; ++mf)
#pragma unroll
    for (int ks = 0; ks < 4; ++ks) {
      bf16x8 a;
#pragma unroll
      for (int j = 0; j < 8; ++j) {
        int row = 32*wv + 16*mf + l15;
        int kk = 32*ks + 8*l4 + j;
        a[j] = f2bf(w2g[row*128 + kk]);
      }
      w2f[mf][ks] = a;
    }
  float bias1[2][4], bias2[2][4];
#pragma unroll
  for (int mf = 0; mf < 2; ++mf)
#pragma unroll
    for (int r = 0; r < 4; ++r) {
      int row = 32*wv + 16*mf + 4*l4 + r;
      bias1[mf][r] = b1g[row];
      bias2[mf][r] = b2g[row];
    }

  // zero x pad region k in [73,96) once (h1 is separate -> stays zero)
  for (int i = tid; i < 64*23; i += 256) {
    int col = i / 23;
    int k = 73 + (i - col*23);
    xb[swzx(col, k)] = 0;
  }

  // ----- feat stage registers (tile t+1) -----
  float4 sf0, sf1, sf2, sf3;
  auto stage = [&](int it2) {
    const int tile = tile0 + it2;
    const int bb = tile >> 9;
    const int pb = (tile & 511) * 2;
    const float* base = inp + ((size_t)((bb*NC + 12 + 4*chq)*NP) + pb + lp2)*NS + 4*s4;
    sf0 = *(const float4*)(base + 0*(size_t)NP*NS);
    sf1 = *(const float4*)(base + 1*(size_t)NP*NS);
    sf2 = *(const float4*)(base + 2*(size_t)NP*NS);
    sf3 = *(const float4*)(base + 3*(size_t)NP*NS);
  };
  auto fill_feats = [&]() {   // consume sf -> LDS
    const float* f0 = (const float*)&sf0;
    const float* f1 = (const float*)&sf1;
    const float* f2 = (const float*)&sf2;
    const float* f3 = (const float*)&sf3;
#pragma unroll
    for (int j = 0; j < 4; ++j) {
      uint2 pk;
      pk.x = cvt_pk_bf16(f0[j], f1[j]);
      pk.y = cvt_pk_bf16(f2[j], f3[j]);
      *(uint2*)&xb[swzx(colb + j, 4*chq)] = pk;
    }
  };
  auto fill_align = [&](int it2) {  // rel/o_n/dir_dif -> k 64..72 (tid<64)
    if (tid < 64) {
      const int tile = tile0 + it2;
      const int bb = tile >> 9;
      const int pb = (tile & 511) * 2;
      const int col = tid;
      const int lp = col >> 5, s = col & 31;
      const int p = pb + lp;
      const float* Rp = ws + (size_t)(bb*NP + p)*12;
      float R[12];
#pragma unroll
      for (int i = 0; i < 12; ++i) R[i] = Rp[i];
      float rel[3], on[3], od[3];
#pragma unroll
      for (int i = 0; i < 3; ++i) {
        rel[i] = inp[(size_t)((bb*NC + 6 + i)*NP + p)*NS + s];
        on[i]  = inp[(size_t)((bb*NC + 3 + i)*NP + p)*NS + s];
        od[i]  = inp[(size_t)((bb*NC + 9 + i)*NP + p)*NS + s];
      }
      float xv[9];
#pragma unroll
      for (int r = 0; r < 3; ++r) {
        xv[r]   = R[3*r]*rel[0] + R[3*r+1]*rel[1] + R[3*r+2]*rel[2];
        xv[3+r] = R[3*r]*on[0]  + R[3*r+1]*on[1]  + R[3*r+2]*on[2];
        xv[6+r] = R[9+r] - (R[3*r]*od[0] + R[3*r+1]*od[1] + R[3*r+2]*od[2]);
      }
      int4 pk;
      pk.x = (int)cvt_pk_bf16(xv[0], xv[1]);
      pk.y = (int)cvt_pk_bf16(xv[2], xv[3]);
      pk.z = (int)cvt_pk_bf16(xv[4], xv[5]);
      pk.w = (int)cvt_pk_bf16(xv[6], xv[7]);
      *(int4*)&xb[swzx(col, 64)] = pk;     // b128, 16B-aligned under swizzle
      xb[swzx(col, 72)] = f2bf(xv[8]);
    }
  };

  // ----- prologue: tile 0 into LDS, tile 1 into regs -----
  stage(0);
  fill_feats();
  fill_align(0);
  if (TPB > 1) stage(1);
  __syncthreads();                       // x(0) visible

  for (int it = 0; it < TPB; ++it) {
    const int tile = tile0 + it;
    const int bb = tile >> 9;
    const int pb = (tile & 511) * 2;

    // ----- layer 1: K=96 (padded), acc rows 32*wv+16*mf -----
    f32x4 acc1[2][4];
#pragma unroll
    for (int mf = 0; mf < 2; ++mf)
#pragma unroll
      for (int nf = 0; nf < 4; ++nf) acc1[mf][nf] = f32x4{0.f,0.f,0.f,0.f};
#pragma unroll
    for (int ks = 0; ks < 3; ++ks) {
      bf16x8 bv[4];
#pragma unroll
      for (int nf = 0; nf < 4; ++nf)
        bv[nf] = *(const bf16x8*)&xb[swzx(16*nf + l15, 32*ks + 8*l4)];
#pragma unroll
      for (int mf = 0; mf < 2; ++mf)
#pragma unroll
        for (int nf = 0; nf < 4; ++nf)
          acc1[mf][nf] = __builtin_amdgcn_mfma_f32_16x16x32_bf16(
              w1f[mf][ks], bv[nf], acc1[mf][nf], 0, 0, 0);
    }

    // ----- h1 -> separate LDS buffer (relu+bias, cvt_pk, b64) -----
#pragma unroll
    for (int mf = 0; mf < 2; ++mf)
#pragma unroll
      for (int nf = 0; nf < 4; ++nf) {
        const int col = 16*nf + l15;
        const int row0 = 32*wv + 16*mf + 4*l4;
        float h0 = fmaxf(acc1[mf][nf][0] + bias1[mf][0], 0.f);
        float h1 = fmaxf(acc1[mf][nf][1] + bias1[mf][1], 0.f);
        float h2 = fmaxf(acc1[mf][nf][2] + bias1[mf][2], 0.f);
        float h3 = fmaxf(acc1[mf][nf][3] + bias1[mf][3], 0.f);
        uint2 pk;
        pk.x = cvt_pk_bf16(h0, h1);
        pk.y = cvt_pk_bf16(h2, h3);
        *(uint2*)&hb[swzh(col, row0)] = pk;
      }
    __syncthreads();                     // h1 visible; x(it) reads done

    // ----- x(it+1) fill overlaps L2(it) compute -----
    if (it + 1 < TPB) { fill_feats(); fill_align(it + 1); }
    if (it + 2 < TPB) stage(it + 2);     // issue next loads early

    // ----- layer 2: K=128 -----
    f32x4 acc2[2][4];
#pragma unroll
    for (int mf = 0; mf < 2; ++mf)
#pragma unroll
      for (int nf = 0; nf < 4; ++nf) acc2[mf][nf] = f32x4{0.f,0.f,0.f,0.f};
#pragma unroll
    for (int ks = 0; ks < 4; ++ks) {
      bf16x8 bv[4];
#pragma unroll
      for (int nf = 0; nf < 4; ++nf)
        bv[nf] = *(const bf16x8*)&hb[swzh(16*nf + l15, 32*ks + 8*l4)];
#pragma unroll
      for (int mf = 0; mf < 2; ++mf)
#pragma unroll
        for (int nf = 0; nf < 4; ++nf)
          acc2[mf][nf] = __builtin_amdgcn_mfma_f32_16x16x32_bf16(
              w2f[mf][ks], bv[nf], acc2[mf][nf], 0, 0, 0);
    }

    // ----- pool over s: nf-pair fmax + DPP16; 2 points per tile -----
#pragma unroll
    for (int mf = 0; mf < 2; ++mf)
#pragma unroll
      for (int r = 0; r < 4; ++r) {
        float v0 = fmaxf(acc2[mf][0][r], acc2[mf][1][r]);   // point 0
        float v1 = fmaxf(acc2[mf][2][r], acc2[mf][3][r]);   // point 1
        v0 = dpp_max16(v0);
        v1 = dpp_max16(v1);
        v0 = fmaxf(v0 + bias2[mf][r], 0.f);
        v1 = fmaxf(v1 + bias2[mf][r], 0.f);
        if (l15 == 0) {
          const int row = 32*wv + 16*mf + 4*l4 + r;
          *(float2*)&out[(size_t)(bb*131 + 3 + row)*NP + pb] = float2{v0, v1};
        }
      }
    __syncthreads();                     // x(it+1) visible; h1 reads done
  }
}

extern "C" void kernel_launch(void* const* d_in, const int* in_sizes, int n_in,
                              void* d_out, int out_size, void* d_ws, size_t ws_size,
                              hipStream_t stream) {
  const float* inp    = (const float*)d_in[0];
  const float* normal = (const float*)d_in[1];
  const float* w1     = (const float*)d_in[2];
  const float* b1     = (const float*)d_in[3];
  const float* w2     = (const float*)d_in[4];
  const float* b2     = (const float*)d_in[5];
  float* out = (float*)d_out;
  float* ws  = (float*)d_ws;    // needs 16384*12*4 = 786,432 B

  frames_kernel<<<dim3((NB*NP)/256), dim3(256), 0, stream>>>(inp, normal, out, ws);
  // tiles of 2 points: 16*512 = 8192; TPB=4 -> 2048 blocks
  mlp_kernel<<<dim3(NB*NP/2/TPB), dim3(256), 0, stream>>>(inp, w1, b1, w2, b2, ws, out);
}

// Round 6
// 85.563 us; speedup vs baseline: 1.3105x; 1.3105x over previous
//
#include <hip/hip_runtime.h>
#include <hip/hip_bf16.h>

#define NB 16
#define NP 1024
#define NS 32
#define NC 76
#define XSTR 104   // xb k-stride (shorts): 96 used + 8 pad; 16B-multiple
#define HSTR 136   // hb k-stride (shorts): 128 used + 8 pad; 16B-multiple
#define TPB 4      // tiles per block; tile = 4 points = 128 MFMA cols

typedef __attribute__((ext_vector_type(8))) short bf16x8;
typedef __attribute__((ext_vector_type(4))) float f32x4;

__device__ inline short f2bf(float f) {
  unsigned u = __builtin_bit_cast(unsigned, f);
  u = u + 0x7fffu + ((u >> 16) & 1u);   // RNE
  return (short)(u >> 16);
}
// packed f32x2 -> bf16x2, one VALU op (RNE)
__device__ inline unsigned cvt_pk_bf16(float lo, float hi) {
  unsigned r;
  asm("v_cvt_pk_bf16_f32 %0, %1, %2" : "=v"(r) : "v"(lo), "v"(hi));
  return r;
}
// Swizzle: fold col bits 4..6 (uniform within any 16-col fragment window, so
// read bank-pattern untouched) into address bits 3..5 (16B-granular: keeps
// b64/b128 alignment). Collision-free for both strides (checked: adjacent-col
// block overlaps never satisfy the xor-difference condition). Spreads the
// fill/h1 write bank-starts to the 4-words/bank floor.
__device__ inline int swzx(int col, int k) {
  return (col * XSTR + k) ^ (((col >> 4) & 7) << 3);
}
__device__ inline int swzh(int col, int k) {
  return (col * HSTR + k) ^ (((col >> 4) & 7) << 3);
}
// max across 16-lane groups via DPP butterfly (no LDS traffic)
__device__ inline float dpp_max16(float v) {
  int x;
  x = __builtin_amdgcn_update_dpp(0, __builtin_bit_cast(int, v), 0xB1, 0xf, 0xf, true);
  v = fmaxf(v, __builtin_bit_cast(float, x));
  x = __builtin_amdgcn_update_dpp(0, __builtin_bit_cast(int, v), 0x4E, 0xf, 0xf, true);
  v = fmaxf(v, __builtin_bit_cast(float, x));
  x = __builtin_amdgcn_update_dpp(0, __builtin_bit_cast(int, v), 0x141, 0xf, 0xf, true);
  v = fmaxf(v, __builtin_bit_cast(float, x));
  x = __builtin_amdgcn_update_dpp(0, __builtin_bit_cast(int, v), 0x140, 0xf, 0xf, true);
  v = fmaxf(v, __builtin_bit_cast(float, x));
  return v;
}

// ---------------- kernel 1: per-(b,p) frames ----------------
__global__ void frames_kernel(const float* __restrict__ inp,
                              const float* __restrict__ normal,
                              float* __restrict__ out, float* __restrict__ ws) {
  const int bp = blockIdx.x * 256 + threadIdx.x;   // 0..16383
  const int b = bp >> 10, p = bp & 1023;

  float azi[3];
#pragma unroll
  for (int i = 0; i < 3; ++i) {
    const float* row = inp + (size_t)((b*NC + 6 + i)*NP + p) * NS;
    float s = 0.f;
#pragma unroll
    for (int q = 0; q < 8; ++q) {
      float4 v = ((const float4*)row)[q];
      s += (v.x + v.y) + (v.z + v.w);
    }
    s -= row[0];                  // mean over s=1..31
    azi[i] = s / 31.f;
  }
  float nr[3];
#pragma unroll
  for (int i = 0; i < 3; ++i) nr[i] = normal[(size_t)(b*NP + p)*3 + i];
  float nn = sqrtf(nr[0]*nr[0] + nr[1]*nr[1] + nr[2]*nr[2]) + 1e-8f;
  nr[0] /= nn; nr[1] /= nn; nr[2] /= nn;
  float au[3] = {azi[0], azi[1], azi[2]};
  float an = sqrtf(au[0]*au[0] + au[1]*au[1] + au[2]*au[2]) + 1e-8f;
  au[0] /= an; au[1] /= an; au[2] /= an;
  float d = au[0]*nr[0] + au[1]*nr[1] + au[2]*nr[2];
  float xax[3] = {au[0] - d*nr[0], au[1] - d*nr[1], au[2] - d*nr[2]};
  float xn = sqrtf(xax[0]*xax[0] + xax[1]*xax[1] + xax[2]*xax[2]) + 1e-8f;
  xax[0] /= xn; xax[1] /= xn; xax[2] /= xn;
  float yax[3] = {nr[1]*xax[2] - nr[2]*xax[1],
                  nr[2]*xax[0] - nr[0]*xax[2],
                  nr[0]*xax[1] - nr[1]*xax[0]};
#pragma unroll
  for (int i = 0; i < 3; ++i)
    out[(size_t)(b*131 + i)*NP + p] = au[i];      // azi_u -> out ch 0..2

  float* w = ws + (size_t)bp * 12;                // R rows + R*azi_u
  w[0]=xax[0]; w[1]=xax[1]; w[2]=xax[2];
  w[3]=yax[0]; w[4]=yax[1]; w[5]=yax[2];
  w[6]=nr[0];  w[7]=nr[1];  w[8]=nr[2];
  w[9]  = xax[0]*au[0] + xax[1]*au[1] + xax[2]*au[2];
  w[10] = yax[0]*au[0] + yax[1]*au[1] + yax[2]*au[2];
  w[11] = nr[0]*au[0]  + nr[1]*au[1]  + nr[2]*au[2];
}

// ---------------- kernel 2: fused MLP + pool ----------------
// 512 threads = 8 waves; wave wv owns output rows 16*wv..16*wv+15.
// Tile = 4 points = 128 cols. x and h1 in SEPARATE LDS buffers -> 2 barriers
// per tile; x(t+1) fill overlaps L2(t) compute.
// xb layout [col=(lp,s)][k]: k 0..63 feats (ch12..75); 64..66 rel; 67..69 o_n;
// 70..72 dir_dif; 73 = 1.0 (bias row, static); 74..95 zero (static).
__global__ __launch_bounds__(512, 2)
void mlp_kernel(const float* __restrict__ inp, const float* __restrict__ w1g,
                const float* __restrict__ b1g, const float* __restrict__ w2g,
                const float* __restrict__ b2g, const float* __restrict__ ws,
                float* __restrict__ out) {
  __shared__ short xb[128 * XSTR];   // 26,624 B
  __shared__ short hb[128 * HSTR];   // 34,816 B
  const int tid = threadIdx.x;
  const int lane = tid & 63;
  const int wv = tid >> 6;          // wave 0..7 -> rows 16*wv..
  const int l15 = lane & 15;
  const int l4 = lane >> 4;         // 0..3

  const int tile0 = blockIdx.x * TPB;

  // fill-phase thread map (feats)
  const int s4  = tid & 7;          // s quad: s = 4*s4..4*s4+3
  const int flp = (tid >> 3) & 3;   // point within tile
  const int chq = tid >> 5;         // channel quad 0..15 -> k = 4*chq
  const int colb = flp*32 + 4*s4;

  // ----- per-wave weight fragments (rows 16*wv+l15); b1 folded at kk=73 -----
  bf16x8 w1f[3];
#pragma unroll
  for (int ks = 0; ks < 3; ++ks) {
    bf16x8 a;
#pragma unroll
    for (int j = 0; j < 8; ++j) {
      int row = 16*wv + l15;
      int kk = 32*ks + 8*l4 + j;
      float v = 0.f;
      if (kk < 73) {
        int c = (kk < 64) ? (kk + 3) : ((kk < 67) ? (kk - 64) : kk);
        v = w1g[row*73 + c];
      } else if (kk == 73) {
        v = b1g[row];               // bias row (x[73] == 1.0)
      }
      a[j] = f2bf(v);
    }
    w1f[ks] = a;
  }
  bf16x8 w2f[4];
#pragma unroll
  for (int ks = 0; ks < 4; ++ks) {
    bf16x8 a;
#pragma unroll
    for (int j = 0; j < 8; ++j) {
      int row = 16*wv + l15;
      int kk = 32*ks + 8*l4 + j;
      a[j] = f2bf(w2g[row*128 + kk]);
    }
    w2f[ks] = a;
  }
  float bias2[4];
#pragma unroll
  for (int r = 0; r < 4; ++r) bias2[r] = b2g[16*wv + 4*l4 + r];

  // static region of xb: k=73 -> 1.0, k in (73,96) -> 0. Written once.
  for (int i = tid; i < 128*23; i += 512) {
    int col = i / 23;
    int k = 73 + (i - col*23);
    xb[swzx(col, k)] = (k == 73) ? (short)0x3F80 : (short)0;
  }

  // ----- register stage for next tile -----
  float4 sf0, sf1, sf2, sf3;    // feats: 4 channels x 4 s
  float sro[9];                 // rel/on/od (tid<128 only)
  auto stage = [&](int it2) {
    const int tile = tile0 + it2;
    const int bb = tile >> 8;
    const int pb = (tile & 255) * 4;
    const float* base = inp + ((size_t)((bb*NC + 12 + 4*chq)*NP) + pb + flp)*NS + 4*s4;
    sf0 = *(const float4*)(base + 0*(size_t)NP*NS);
    sf1 = *(const float4*)(base + 1*(size_t)NP*NS);
    sf2 = *(const float4*)(base + 2*(size_t)NP*NS);
    sf3 = *(const float4*)(base + 3*(size_t)NP*NS);
    if (tid < 128) {
      const int lp = tid >> 5, s = tid & 31;
      const int p = pb + lp;
#pragma unroll
      for (int i = 0; i < 3; ++i) {
        sro[i]   = inp[(size_t)((bb*NC + 6 + i)*NP + p)*NS + s];
        sro[3+i] = inp[(size_t)((bb*NC + 3 + i)*NP + p)*NS + s];
        sro[6+i] = inp[(size_t)((bb*NC + 9 + i)*NP + p)*NS + s];
      }
    }
  };
  auto fill = [&](int it2) {    // consume staged regs -> xb
    const float* f0 = (const float*)&sf0;
    const float* f1 = (const float*)&sf1;
    const float* f2 = (const float*)&sf2;
    const float* f3 = (const float*)&sf3;
#pragma unroll
    for (int j = 0; j < 4; ++j) {
      uint2 pk;
      pk.x = cvt_pk_bf16(f0[j], f1[j]);
      pk.y = cvt_pk_bf16(f2[j], f3[j]);
      *(uint2*)&xb[swzx(colb + j, 4*chq)] = pk;
    }
    if (tid < 128) {
      const int tile = tile0 + it2;
      const int bb = tile >> 8;
      const int pb = (tile & 255) * 4;
      const int col = tid;
      const int lp = col >> 5;
      const float* Rp = ws + (size_t)(bb*NP + pb + lp)*12;
      float R[12];
#pragma unroll
      for (int i = 0; i < 12; ++i) R[i] = Rp[i];
      float xv[9];
#pragma unroll
      for (int r = 0; r < 3; ++r) {
        xv[r]   = R[3*r]*sro[0] + R[3*r+1]*sro[1] + R[3*r+2]*sro[2];
        xv[3+r] = R[3*r]*sro[3] + R[3*r+1]*sro[4] + R[3*r+2]*sro[5];
        xv[6+r] = R[9+r] - (R[3*r]*sro[6] + R[3*r+1]*sro[7] + R[3*r+2]*sro[8]);
      }
      int4 pk;
      pk.x = (int)cvt_pk_bf16(xv[0], xv[1]);
      pk.y = (int)cvt_pk_bf16(xv[2], xv[3]);
      pk.z = (int)cvt_pk_bf16(xv[4], xv[5]);
      pk.w = (int)cvt_pk_bf16(xv[6], xv[7]);
      *(int4*)&xb[swzx(col, 64)] = pk;     // k 64..71 (16B aligned)
      xb[swzx(col, 72)] = f2bf(xv[8]);
    }
  };

  // ----- prologue -----
  stage(0);
  fill(0);
  stage(1);
  __syncthreads();                       // x(0) visible

  for (int it = 0; it < TPB; ++it) {
    const int tile = tile0 + it;
    const int bb = tile >> 8;
    const int pb = (tile & 255) * 4;

    // ----- layer 1: h1 = relu(w1 @ x) (bias via ones-row), K=96 -----
    f32x4 acc1[8];
#pragma unroll
    for (int nf = 0; nf < 8; ++nf) acc1[nf] = f32x4{0.f,0.f,0.f,0.f};
#pragma unroll
    for (int ks = 0; ks < 3; ++ks) {
      bf16x8 bv[8];
#pragma unroll
      for (int nf = 0; nf < 8; ++nf)
        bv[nf] = *(const bf16x8*)&xb[swzx(16*nf + l15, 32*ks + 8*l4)];
#pragma unroll
      for (int nf = 0; nf < 8; ++nf)
        acc1[nf] = __builtin_amdgcn_mfma_f32_16x16x32_bf16(
            w1f[ks], bv[nf], acc1[nf], 0, 0, 0);
    }

    // h1 -> hb (relu, cvt_pk, b64)
#pragma unroll
    for (int nf = 0; nf < 8; ++nf) {
      const int col = 16*nf + l15;
      const int row0 = 16*wv + 4*l4;
      uint2 pk;
      pk.x = cvt_pk_bf16(fmaxf(acc1[nf][0], 0.f), fmaxf(acc1[nf][1], 0.f));
      pk.y = cvt_pk_bf16(fmaxf(acc1[nf][2], 0.f), fmaxf(acc1[nf][3], 0.f));
      *(uint2*)&hb[swzh(col, row0)] = pk;
    }
    __syncthreads();                     // xb reads done; hb visible

    // x(it+1) fill overlaps layer-2 compute (separate buffers)
    if (it + 1 < TPB) fill(it + 1);
    if (it + 2 < TPB) stage(it + 2);

    // ----- layer 2: h2 = relu(w2 @ h1 + b2), K=128 -----
    f32x4 acc2[8];
#pragma unroll
    for (int nf = 0; nf < 8; ++nf) acc2[nf] = f32x4{0.f,0.f,0.f,0.f};
#pragma unroll
    for (int ks = 0; ks < 4; ++ks) {
      bf16x8 bv[8];
#pragma unroll
      for (int nf = 0; nf < 8; ++nf)
        bv[nf] = *(const bf16x8*)&hb[swzh(16*nf + l15, 32*ks + 8*l4)];
#pragma unroll
      for (int nf = 0; nf < 8; ++nf)
        acc2[nf] = __builtin_amdgcn_mfma_f32_16x16x32_bf16(
            w2f[ks], bv[nf], acc2[nf], 0, 0, 0);
    }

    // ----- relu + max-pool over s (DPP butterfly) + store -----
#pragma unroll
    for (int r = 0; r < 4; ++r)
#pragma unroll
      for (int lp = 0; lp < 4; ++lp) {
        float v = fmaxf(fmaxf(acc2[2*lp][r], acc2[2*lp+1][r]) + bias2[r], 0.f);
        v = dpp_max16(v);
        if (l15 == lp) {
          const int row = 16*wv + 4*l4 + r;
          out[(size_t)(bb*131 + 3 + row)*NP + pb + lp] = v;
        }
      }
    __syncthreads();                     // hb reads done; x(it+1) visible
  }
}

extern "C" void kernel_launch(void* const* d_in, const int* in_sizes, int n_in,
                              void* d_out, int out_size, void* d_ws, size_t ws_size,
                              hipStream_t stream) {
  const float* inp    = (const float*)d_in[0];
  const float* normal = (const float*)d_in[1];
  const float* w1     = (const float*)d_in[2];
  const float* b1     = (const float*)d_in[3];
  const float* w2     = (const float*)d_in[4];
  const float* b2     = (const float*)d_in[5];
  float* out = (float*)d_out;
  float* ws  = (float*)d_ws;    // needs 16384*12*4 = 786,432 B

  frames_kernel<<<dim3((NB*NP)/256), dim3(256), 0, stream>>>(inp, normal, out, ws);
  mlp_kernel<<<dim3(NB*NP/4/TPB), dim3(512), 0, stream>>>(inp, w1, b1, w2, b2, ws, out);
}

// Round 7
// 63.061 us; speedup vs baseline: 1.7781x; 1.3568x over previous
//
#include <hip/hip_runtime.h>
#include <hip/hip_bf16.h>

#define NB 16
#define NP 1024
#define NS 32
#define NC 76
#define XSTR 104   // xb k-stride (shorts): 96 used + 8 pad; 16B-multiple
#define HSTR 136   // hb k-stride (shorts): 128 used + 8 pad; 16B-multiple
#define TPB 16     // tiles per block; tile = 4 points = 128 MFMA cols; grid = 256 = 1 block/CU

typedef __attribute__((ext_vector_type(8))) short bf16x8;
typedef __attribute__((ext_vector_type(4))) float f32x4;

__device__ inline short f2bf(float f) {
  unsigned u = __builtin_bit_cast(unsigned, f);
  u = u + 0x7fffu + ((u >> 16) & 1u);   // RNE
  return (short)(u >> 16);
}
// packed f32x2 -> bf16x2, one VALU op (RNE)
__device__ inline unsigned cvt_pk_bf16(float lo, float hi) {
  unsigned r;
  asm("v_cvt_pk_bf16_f32 %0, %1, %2" : "=v"(r) : "v"(lo), "v"(hi));
  return r;
}
// Swizzle: fold col bits 4..6 (uniform within any 16-col fragment window ->
// read bank-pattern untouched) into addr bits 3..5 (16B-granular: keeps
// b64/b128 alignment). Bijective, collision-free for both strides.
__device__ inline int swzx(int col, int k) {
  return (col * XSTR + k) ^ (((col >> 4) & 7) << 3);
}
__device__ inline int swzh(int col, int k) {
  return (col * HSTR + k) ^ (((col >> 4) & 7) << 3);
}
// max across 16-lane groups via DPP butterfly (no LDS traffic)
__device__ inline float dpp_max16(float v) {
  int x;
  x = __builtin_amdgcn_update_dpp(0, __builtin_bit_cast(int, v), 0xB1, 0xf, 0xf, true);
  v = fmaxf(v, __builtin_bit_cast(float, x));
  x = __builtin_amdgcn_update_dpp(0, __builtin_bit_cast(int, v), 0x4E, 0xf, 0xf, true);
  v = fmaxf(v, __builtin_bit_cast(float, x));
  x = __builtin_amdgcn_update_dpp(0, __builtin_bit_cast(int, v), 0x141, 0xf, 0xf, true);
  v = fmaxf(v, __builtin_bit_cast(float, x));
  x = __builtin_amdgcn_update_dpp(0, __builtin_bit_cast(int, v), 0x140, 0xf, 0xf, true);
  v = fmaxf(v, __builtin_bit_cast(float, x));
  return v;
}

// ---------------- kernel 1: per-(b,p) frames ----------------
__global__ void frames_kernel(const float* __restrict__ inp,
                              const float* __restrict__ normal,
                              float* __restrict__ out, float* __restrict__ ws) {
  const int bp = blockIdx.x * 256 + threadIdx.x;   // 0..16383
  const int b = bp >> 10, p = bp & 1023;

  float azi[3];
#pragma unroll
  for (int i = 0; i < 3; ++i) {
    const float* row = inp + (size_t)((b*NC + 6 + i)*NP + p) * NS;
    float s = 0.f;
#pragma unroll
    for (int q = 0; q < 8; ++q) {
      float4 v = ((const float4*)row)[q];
      s += (v.x + v.y) + (v.z + v.w);
    }
    s -= row[0];                  // mean over s=1..31
    azi[i] = s / 31.f;
  }
  float nr[3];
#pragma unroll
  for (int i = 0; i < 3; ++i) nr[i] = normal[(size_t)(b*NP + p)*3 + i];
  float nn = sqrtf(nr[0]*nr[0] + nr[1]*nr[1] + nr[2]*nr[2]) + 1e-8f;
  nr[0] /= nn; nr[1] /= nn; nr[2] /= nn;
  float au[3] = {azi[0], azi[1], azi[2]};
  float an = sqrtf(au[0]*au[0] + au[1]*au[1] + au[2]*au[2]) + 1e-8f;
  au[0] /= an; au[1] /= an; au[2] /= an;
  float d = au[0]*nr[0] + au[1]*nr[1] + au[2]*nr[2];
  float xax[3] = {au[0] - d*nr[0], au[1] - d*nr[1], au[2] - d*nr[2]};
  float xn = sqrtf(xax[0]*xax[0] + xax[1]*xax[1] + xax[2]*xax[2]) + 1e-8f;
  xax[0] /= xn; xax[1] /= xn; xax[2] /= xn;
  float yax[3] = {nr[1]*xax[2] - nr[2]*xax[1],
                  nr[2]*xax[0] - nr[0]*xax[2],
                  nr[0]*xax[1] - nr[1]*xax[0]};
#pragma unroll
  for (int i = 0; i < 3; ++i)
    out[(size_t)(b*131 + i)*NP + p] = au[i];      // azi_u -> out ch 0..2

  float* w = ws + (size_t)bp * 12;                // R rows + R*azi_u
  w[0]=xax[0]; w[1]=xax[1]; w[2]=xax[2];
  w[3]=yax[0]; w[4]=yax[1]; w[5]=yax[2];
  w[6]=nr[0];  w[7]=nr[1];  w[8]=nr[2];
  w[9]  = xax[0]*au[0] + xax[1]*au[1] + xax[2]*au[2];
  w[10] = yax[0]*au[0] + yax[1]*au[1] + yax[2]*au[2];
  w[11] = nr[0]*au[0]  + nr[1]*au[1]  + nr[2]*au[2];
}

// ---------------- kernel 2: fused MLP + pool ----------------
// 512 threads = 8 waves arranged 4 (row-stripes) x 2 (col-halves):
//   wr = wv>>1 owns rows 32*wr..32*wr+31 (mf=0,1)
//   wc = wv&1  owns cols 64*wc..64*wc+63 (nf=0..3)
// -> each B-fragment read shared by 4 waves instead of 8 (halved LDS volume).
// Tile = 4 points = 128 cols. Separate xb/hb buffers; 2 barriers/tile.
// xb [col][k]: k 0..63 feats(ch12..75); 64..66 rel; 67..69 o_n; 70..72 dir_dif;
//              73 = 1.0 (bias row, static); 74..95 = 0 (static).
__global__ __launch_bounds__(512, 2)
void mlp_kernel(const float* __restrict__ inp, const float* __restrict__ w1g,
                const float* __restrict__ b1g, const float* __restrict__ w2g,
                const float* __restrict__ b2g, const float* __restrict__ ws,
                float* __restrict__ out) {
  __shared__ short xb[128 * XSTR];   // 26,624 B
  __shared__ short hb[128 * HSTR];   // 34,816 B
  const int tid = threadIdx.x;
  const int lane = tid & 63;
  const int wv = tid >> 6;
  const int wr = wv >> 1;           // row-stripe 0..3 -> rows 32*wr..
  const int wc = wv & 1;            // col-half 0..1 -> cols 64*wc..
  const int l15 = lane & 15;
  const int l4 = lane >> 4;         // 0..3

  const int tile0 = blockIdx.x * TPB;

  // fill-phase thread map (feats)
  const int s4  = tid & 7;          // s quad: s = 4*s4..4*s4+3
  const int flp = (tid >> 3) & 3;   // point within tile
  const int chq = tid >> 5;         // channel quad 0..15 -> k = 4*chq
  const int colb = flp*32 + 4*s4;

  // ----- per-wave weight fragments (rows 32*wr+16*mf+l15); b1 folded at kk=73
  bf16x8 w1f[2][3];
#pragma unroll
  for (int mf = 0; mf < 2; ++mf)
#pragma unroll
    for (int ks = 0; ks < 3; ++ks) {
      bf16x8 a;
#pragma unroll
      for (int j = 0; j < 8; ++j) {
        int row = 32*wr + 16*mf + l15;
        int kk = 32*ks + 8*l4 + j;
        float v = 0.f;
        if (kk < 73) {
          int c = (kk < 64) ? (kk + 3) : ((kk < 67) ? (kk - 64) : kk);
          v = w1g[row*73 + c];
        } else if (kk == 73) {
          v = b1g[row];             // bias row (x[73] == 1.0)
        }
        a[j] = f2bf(v);
      }
      w1f[mf][ks] = a;
    }
  bf16x8 w2f[2][4];
#pragma unroll
  for (int mf = 0; mf < 2; ++mf)
#pragma unroll
    for (int ks = 0; ks < 4; ++ks) {
      bf16x8 a;
#pragma unroll
      for (int j = 0; j < 8; ++j) {
        int row = 32*wr + 16*mf + l15;
        int kk = 32*ks + 8*l4 + j;
        a[j] = f2bf(w2g[row*128 + kk]);
      }
      w2f[mf][ks] = a;
    }
  float bias2[2][4];
#pragma unroll
  for (int mf = 0; mf < 2; ++mf)
#pragma unroll
    for (int r = 0; r < 4; ++r)
      bias2[mf][r] = b2g[32*wr + 16*mf + 4*l4 + r];

  // static region of xb: k=73 -> 1.0, (73,96) -> 0. Written once.
  for (int i = tid; i < 128*23; i += 512) {
    int col = i / 23;
    int k = 73 + (i - col*23);
    xb[swzx(col, k)] = (k == 73) ? (short)0x3F80 : (short)0;
  }

  // ----- feat staging registers for next tile -----
  float4 sf0, sf1, sf2, sf3;
  auto stage = [&](int it2) {
    const int tile = tile0 + it2;
    const int bb = tile >> 8;
    const int pb = (tile & 255) * 4;
    const float* base = inp + ((size_t)((bb*NC + 12 + 4*chq)*NP) + pb + flp)*NS + 4*s4;
    sf0 = *(const float4*)(base + 0*(size_t)NP*NS);
    sf1 = *(const float4*)(base + 1*(size_t)NP*NS);
    sf2 = *(const float4*)(base + 2*(size_t)NP*NS);
    sf3 = *(const float4*)(base + 3*(size_t)NP*NS);
  };
  auto fill = [&](int it2) {    // staged feats + direct-load aligned rows -> xb
    const float* f0 = (const float*)&sf0;
    const float* f1 = (const float*)&sf1;
    const float* f2 = (const float*)&sf2;
    const float* f3 = (const float*)&sf3;
#pragma unroll
    for (int j = 0; j < 4; ++j) {
      uint2 pk;
      pk.x = cvt_pk_bf16(f0[j], f1[j]);
      pk.y = cvt_pk_bf16(f2[j], f3[j]);
      *(uint2*)&xb[swzx(colb + j, 4*chq)] = pk;
    }
    if (tid < 128) {
      const int tile = tile0 + it2;
      const int bb = tile >> 8;
      const int pb = (tile & 255) * 4;
      const int col = tid;
      const int lp = col >> 5, s = col & 31;
      const int p = pb + lp;
      const float* Rp = ws + (size_t)(bb*NP + p)*12;
      float R[12];
#pragma unroll
      for (int i = 0; i < 12; ++i) R[i] = Rp[i];
      float rel[3], on[3], od[3];
#pragma unroll
      for (int i = 0; i < 3; ++i) {
        rel[i] = inp[(size_t)((bb*NC + 6 + i)*NP + p)*NS + s];
        on[i]  = inp[(size_t)((bb*NC + 3 + i)*NP + p)*NS + s];
        od[i]  = inp[(size_t)((bb*NC + 9 + i)*NP + p)*NS + s];
      }
      float xv[9];
#pragma unroll
      for (int r = 0; r < 3; ++r) {
        xv[r]   = R[3*r]*rel[0] + R[3*r+1]*rel[1] + R[3*r+2]*rel[2];
        xv[3+r] = R[3*r]*on[0]  + R[3*r+1]*on[1]  + R[3*r+2]*on[2];
        xv[6+r] = R[9+r] - (R[3*r]*od[0] + R[3*r+1]*od[1] + R[3*r+2]*od[2]);
      }
      int4 pk;
      pk.x = (int)cvt_pk_bf16(xv[0], xv[1]);
      pk.y = (int)cvt_pk_bf16(xv[2], xv[3]);
      pk.z = (int)cvt_pk_bf16(xv[4], xv[5]);
      pk.w = (int)cvt_pk_bf16(xv[6], xv[7]);
      *(int4*)&xb[swzx(col, 64)] = pk;     // k 64..71
      xb[swzx(col, 72)] = f2bf(xv[8]);
    }
  };

  // ----- prologue -----
  stage(0);
  fill(0);
  stage(1);
  __syncthreads();                       // x(0) visible

  for (int it = 0; it < TPB; ++it) {
    const int tile = tile0 + it;
    const int bb = tile >> 8;
    const int pb = (tile & 255) * 4;

    // ----- layer 1: h1 = relu(w1 @ x) (bias via ones-row), K=96 -----
    f32x4 acc1[2][4];
#pragma unroll
    for (int mf = 0; mf < 2; ++mf)
#pragma unroll
      for (int nf = 0; nf < 4; ++nf) acc1[mf][nf] = f32x4{0.f,0.f,0.f,0.f};
#pragma unroll
    for (int ks = 0; ks < 3; ++ks) {
      bf16x8 bv[4];
#pragma unroll
      for (int nf = 0; nf < 4; ++nf)
        bv[nf] = *(const bf16x8*)&xb[swzx(64*wc + 16*nf + l15, 32*ks + 8*l4)];
#pragma unroll
      for (int mf = 0; mf < 2; ++mf)
#pragma unroll
        for (int nf = 0; nf < 4; ++nf)
          acc1[mf][nf] = __builtin_amdgcn_mfma_f32_16x16x32_bf16(
              w1f[mf][ks], bv[nf], acc1[mf][nf], 0, 0, 0);
    }

    // h1 -> hb (relu, cvt_pk, b64)
#pragma unroll
    for (int mf = 0; mf < 2; ++mf)
#pragma unroll
      for (int nf = 0; nf < 4; ++nf) {
        const int col = 64*wc + 16*nf + l15;
        const int row0 = 32*wr + 16*mf + 4*l4;
        uint2 pk;
        pk.x = cvt_pk_bf16(fmaxf(acc1[mf][nf][0], 0.f), fmaxf(acc1[mf][nf][1], 0.f));
        pk.y = cvt_pk_bf16(fmaxf(acc1[mf][nf][2], 0.f), fmaxf(acc1[mf][nf][3], 0.f));
        *(uint2*)&hb[swzh(col, row0)] = pk;
      }
    __syncthreads();                     // xb reads done; hb visible

    // x(it+1) fill overlaps layer-2 compute
    if (it + 1 < TPB) fill(it + 1);
    if (it + 2 < TPB) stage(it + 2);

    // ----- layer 2: h2 = relu(w2 @ h1 + b2), K=128 -----
    f32x4 acc2[2][4];
#pragma unroll
    for (int mf = 0; mf < 2; ++mf)
#pragma unroll
      for (int nf = 0; nf < 4; ++nf) acc2[mf][nf] = f32x4{0.f,0.f,0.f,0.f};
#pragma unroll
    for (int ks = 0; ks < 4; ++ks) {
      bf16x8 bv[4];
#pragma unroll
      for (int nf = 0; nf < 4; ++nf)
        bv[nf] = *(const bf16x8*)&hb[swzh(64*wc + 16*nf + l15, 32*ks + 8*l4)];
#pragma unroll
      for (int mf = 0; mf < 2; ++mf)
#pragma unroll
        for (int nf = 0; nf < 4; ++nf)
          acc2[mf][nf] = __builtin_amdgcn_mfma_f32_16x16x32_bf16(
              w2f[mf][ks], bv[nf], acc2[mf][nf], 0, 0, 0);
    }

    // ----- relu + max-pool over s (DPP butterfly) + store -----
    // wave covers points pb+2*wc (nf 0,1) and pb+2*wc+1 (nf 2,3)
#pragma unroll
    for (int mf = 0; mf < 2; ++mf)
#pragma unroll
      for (int r = 0; r < 4; ++r) {
        float v0 = fmaxf(acc2[mf][0][r], acc2[mf][1][r]);
        float v1 = fmaxf(acc2[mf][2][r], acc2[mf][3][r]);
        v0 = dpp_max16(v0);
        v1 = dpp_max16(v1);
        v0 = fmaxf(v0 + bias2[mf][r], 0.f);
        v1 = fmaxf(v1 + bias2[mf][r], 0.f);
        if (l15 == 0) {
          const int row = 32*wr + 16*mf + 4*l4 + r;
          *(float2*)&out[(size_t)(bb*131 + 3 + row)*NP + pb + 2*wc] = float2{v0, v1};
        }
      }
    __syncthreads();                     // hb reads done; x(it+1) visible
  }
}

extern "C" void kernel_launch(void* const* d_in, const int* in_sizes, int n_in,
                              void* d_out, int out_size, void* d_ws, size_t ws_size,
                              hipStream_t stream) {
  const float* inp    = (const float*)d_in[0];
  const float* normal = (const float*)d_in[1];
  const float* w1     = (const float*)d_in[2];
  const float* b1     = (const float*)d_in[3];
  const float* w2     = (const float*)d_in[4];
  const float* b2     = (const float*)d_in[5];
  float* out = (float*)d_out;
  float* ws  = (float*)d_ws;    // needs 16384*12*4 = 786,432 B

  frames_kernel<<<dim3((NB*NP)/256), dim3(256), 0, stream>>>(inp, normal, out, ws);
  // 4096 tiles / TPB=16 -> 256 blocks = 1 per CU
  mlp_kernel<<<dim3(NB*NP/4/TPB), dim3(512), 0, stream>>>(inp, w1, b1, w2, b2, ws, out);
}

// Round 8
// 60.818 us; speedup vs baseline: 1.8437x; 1.0369x over previous
//
#include <hip/hip_runtime.h>
#include <hip/hip_bf16.h>

#define NB 16
#define NP 1024
#define NS 32
#define NC 76
#define XSTR 104   // xb k-stride (shorts): 96 used + 8 pad; 16B-multiple
#define HSTR 136   // hb k-stride (shorts): 128 used + 8 pad; 16B-multiple
#define TPB 16     // tiles per block; tile = 4 points; grid = 256 = 1 block/CU

typedef __attribute__((ext_vector_type(8))) short bf16x8;
typedef __attribute__((ext_vector_type(4))) float f32x4;

__device__ inline short f2bf(float f) {
  unsigned u = __builtin_bit_cast(unsigned, f);
  u = u + 0x7fffu + ((u >> 16) & 1u);   // RNE
  return (short)(u >> 16);
}
__device__ inline unsigned cvt_pk_bf16(float lo, float hi) {
  unsigned r;
  asm("v_cvt_pk_bf16_f32 %0, %1, %2" : "=v"(r) : "v"(lo), "v"(hi));
  return r;
}
// Swizzle: fold col bits 4..6 (uniform per 16-col fragment window -> read
// bank-pattern untouched) into addr bits 3..5 (16B-granular). Bijective.
__device__ inline int swzx(int col, int k) {
  return (col * XSTR + k) ^ (((col >> 4) & 7) << 3);
}
__device__ inline int swzh(int col, int k) {
  return (col * HSTR + k) ^ (((col >> 4) & 7) << 3);
}
// max across 16-lane groups via DPP butterfly
__device__ inline float dpp_max16(float v) {
  int x;
  x = __builtin_amdgcn_update_dpp(0, __builtin_bit_cast(int, v), 0xB1, 0xf, 0xf, true);
  v = fmaxf(v, __builtin_bit_cast(float, x));
  x = __builtin_amdgcn_update_dpp(0, __builtin_bit_cast(int, v), 0x4E, 0xf, 0xf, true);
  v = fmaxf(v, __builtin_bit_cast(float, x));
  x = __builtin_amdgcn_update_dpp(0, __builtin_bit_cast(int, v), 0x141, 0xf, 0xf, true);
  v = fmaxf(v, __builtin_bit_cast(float, x));
  x = __builtin_amdgcn_update_dpp(0, __builtin_bit_cast(int, v), 0x140, 0xf, 0xf, true);
  v = fmaxf(v, __builtin_bit_cast(float, x));
  return v;
}

// ---------------- single fused kernel: frames + MLP + pool ----------------
// 512 threads = 8 waves in a 4x2 grid: wr=wv>>1 -> rows 32*wr.., wc=wv&1 ->
// cols 64*wc.. Tile = 4 points = 128 cols. xb/hb DOUBLE-buffered -> 1 barrier
// per tile:  L2(t)+pool | L1(t+1)+h1store | fill(t+2) | stage(t+3) | bar.
// Frames (azi mean + Gram-Schmidt R) computed in-register inside fill via
// 32-lane shuffle reduction; azi_u written to out ch 0..2 there.
// xb [col][k]: 0..63 feats(ch12..75); 64..66 R*rel; 67..69 R*o_n; 70..72
// dir_dif; 73 = 1.0 (bias row, static); 74..95 = 0 (static).
__global__ __launch_bounds__(512, 2)
void mlp_kernel(const float* __restrict__ inp, const float* __restrict__ w1g,
                const float* __restrict__ b1g, const float* __restrict__ w2g,
                const float* __restrict__ b2g, const float* __restrict__ normal,
                float* __restrict__ out) {
  __shared__ short xb[2][128 * XSTR];   // 2 x 26,624 B
  __shared__ short hb[2][128 * HSTR];   // 2 x 34,816 B
  const int tid = threadIdx.x;
  const int lane = tid & 63;
  const int wv = tid >> 6;
  const int wr = wv >> 1;           // row-stripe 0..3 -> rows 32*wr..
  const int wc = wv & 1;            // col-half 0..1 -> cols 64*wc..
  const int l15 = lane & 15;
  const int l4 = lane >> 4;         // 0..3

  const int tile0 = blockIdx.x * TPB;

  // fill-phase thread map (feats)
  const int s4  = tid & 7;          // s quad
  const int flp = (tid >> 3) & 3;   // point within tile
  const int chq = tid >> 5;         // channel quad 0..15 -> k = 4*chq
  const int colb = flp*32 + 4*s4;

  // ----- weight fragments (rows 32*wr+16*mf+l15); b1 folded at kk=73 -----
  bf16x8 w1f[2][3];
#pragma unroll
  for (int mf = 0; mf < 2; ++mf)
#pragma unroll
    for (int ks = 0; ks < 3; ++ks) {
      bf16x8 a;
#pragma unroll
      for (int j = 0; j < 8; ++j) {
        int row = 32*wr + 16*mf + l15;
        int kk = 32*ks + 8*l4 + j;
        float v = 0.f;
        if (kk < 73) {
          int c = (kk < 64) ? (kk + 3) : ((kk < 67) ? (kk - 64) : kk);
          v = w1g[row*73 + c];
        } else if (kk == 73) {
          v = b1g[row];
        }
        a[j] = f2bf(v);
      }
      w1f[mf][ks] = a;
    }
  bf16x8 w2f[2][4];
#pragma unroll
  for (int mf = 0; mf < 2; ++mf)
#pragma unroll
    for (int ks = 0; ks < 4; ++ks) {
      bf16x8 a;
#pragma unroll
      for (int j = 0; j < 8; ++j) {
        int row = 32*wr + 16*mf + l15;
        int kk = 32*ks + 8*l4 + j;
        a[j] = f2bf(w2g[row*128 + kk]);
      }
      w2f[mf][ks] = a;
    }
  float bias2[2][4];
#pragma unroll
  for (int mf = 0; mf < 2; ++mf)
#pragma unroll
    for (int r = 0; r < 4; ++r)
      bias2[mf][r] = b2g[32*wr + 16*mf + 4*l4 + r];

  // static pad region of BOTH xb buffers: k=73 -> 1.0, (73,96) -> 0
  for (int i = tid; i < 2*128*23; i += 512) {
    int bufi = i / (128*23);
    int r = i - bufi*(128*23);
    int col = r / 23;
    int k = 73 + (r - col*23);
    xb[bufi][swzx(col, k)] = (k == 73) ? (short)0x3F80 : (short)0;
  }

  // ----- staging registers for tile t+? -----
  float4 sf0, sf1, sf2, sf3;    // feats: 4 channels x 4 s
  float sro[9];                 // rel/o_n/o_dir for (p, s) (tid<128)
  auto stage = [&](int it2) {
    const int tile = tile0 + it2;
    const int bb = tile >> 8;
    const int pb = (tile & 255) * 4;
    const float* base = inp + ((size_t)((bb*NC + 12 + 4*chq)*NP) + pb + flp)*NS + 4*s4;
    sf0 = *(const float4*)(base + 0*(size_t)NP*NS);
    sf1 = *(const float4*)(base + 1*(size_t)NP*NS);
    sf2 = *(const float4*)(base + 2*(size_t)NP*NS);
    sf3 = *(const float4*)(base + 3*(size_t)NP*NS);
    if (tid < 128) {
      const int lp = tid >> 5, s = tid & 31;
      const int p = pb + lp;
#pragma unroll
      for (int i = 0; i < 3; ++i) {
        sro[i]   = inp[(size_t)((bb*NC + 6 + i)*NP + p)*NS + s];   // rel
        sro[3+i] = inp[(size_t)((bb*NC + 3 + i)*NP + p)*NS + s];   // o_n
        sro[6+i] = inp[(size_t)((bb*NC + 9 + i)*NP + p)*NS + s];   // o_dir
      }
    }
  };

  auto fill = [&](int it2, int bufi) {
    // feats from staged regs
    const float* f0 = (const float*)&sf0;
    const float* f1 = (const float*)&sf1;
    const float* f2 = (const float*)&sf2;
    const float* f3 = (const float*)&sf3;
#pragma unroll
    for (int j = 0; j < 4; ++j) {
      uint2 pk;
      pk.x = cvt_pk_bf16(f0[j], f1[j]);
      pk.y = cvt_pk_bf16(f2[j], f3[j]);
      *(uint2*)&xb[bufi][swzx(colb + j, 4*chq)] = pk;
    }
    // frames + aligned rows (tid<128: col=(lp,s))
    if (tid < 128) {
      const int tile = tile0 + it2;
      const int bb = tile >> 8;
      const int pb = (tile & 255) * 4;
      const int col = tid;
      const int lp = col >> 5, s = col & 31;
      const int p = pb + lp;
      // azi = mean over s=1..31 of rel (32-lane butterfly within s-group)
      float az[3];
#pragma unroll
      for (int i = 0; i < 3; ++i) {
        float sum = sro[i];
#pragma unroll
        for (int m = 1; m < 32; m <<= 1) sum += __shfl_xor(sum, m);
        float v0 = __shfl(sro[i], lane & 32);    // s == 0 lane of this group
        az[i] = (sum - v0) * (1.f/31.f);
      }
      // n = unit(normal), au = unit(azi)
      float nr[3];
#pragma unroll
      for (int i = 0; i < 3; ++i) nr[i] = normal[(size_t)(bb*NP + p)*3 + i];
      float nn = sqrtf(nr[0]*nr[0] + nr[1]*nr[1] + nr[2]*nr[2]) + 1e-8f;
      nr[0] /= nn; nr[1] /= nn; nr[2] /= nn;
      float an = sqrtf(az[0]*az[0] + az[1]*az[1] + az[2]*az[2]) + 1e-8f;
      float au[3] = {az[0]/an, az[1]/an, az[2]/an};
      float d = au[0]*nr[0] + au[1]*nr[1] + au[2]*nr[2];
      float xax[3] = {au[0] - d*nr[0], au[1] - d*nr[1], au[2] - d*nr[2]};
      float xn = sqrtf(xax[0]*xax[0] + xax[1]*xax[1] + xax[2]*xax[2]) + 1e-8f;
      xax[0] /= xn; xax[1] /= xn; xax[2] /= xn;
      float yax[3] = {nr[1]*xax[2] - nr[2]*xax[1],
                      nr[2]*xax[0] - nr[0]*xax[2],
                      nr[0]*xax[1] - nr[1]*xax[0]};
      // azi_u -> out channels 0..2 (lanes s=0,1,2 of each point write one)
      if (s < 3) {
        float o = (s == 0) ? au[0] : ((s == 1) ? au[1] : au[2]);
        out[(size_t)(bb*131 + s)*NP + p] = o;
      }
      // aligned rows: R*rel, R*o_n, R*au - R*o_dir
      float xv[9];
#pragma unroll
      for (int r = 0; r < 3; ++r) {
        const float* Rr = (r == 0) ? xax : ((r == 1) ? yax : nr);
        xv[r]   = Rr[0]*sro[0] + Rr[1]*sro[1] + Rr[2]*sro[2];
        xv[3+r] = Rr[0]*sro[3] + Rr[1]*sro[4] + Rr[2]*sro[5];
        xv[6+r] = (Rr[0]*au[0] + Rr[1]*au[1] + Rr[2]*au[2])
                - (Rr[0]*sro[6] + Rr[1]*sro[7] + Rr[2]*sro[8]);
      }
      int4 pk;
      pk.x = (int)cvt_pk_bf16(xv[0], xv[1]);
      pk.y = (int)cvt_pk_bf16(xv[2], xv[3]);
      pk.z = (int)cvt_pk_bf16(xv[4], xv[5]);
      pk.w = (int)cvt_pk_bf16(xv[6], xv[7]);
      *(int4*)&xb[bufi][swzx(col, 64)] = pk;
      xb[bufi][swzx(col, 72)] = f2bf(xv[8]);
    }
  };

  // per-tile compute phases
  f32x4 acc2[2][4];
  auto layer1_h1 = [&](int tt) {      // L1 from xb[tt&1] -> hb[tt&1]
    f32x4 acc1[2][4];
#pragma unroll
    for (int mf = 0; mf < 2; ++mf)
#pragma unroll
      for (int nf = 0; nf < 4; ++nf) acc1[mf][nf] = f32x4{0.f,0.f,0.f,0.f};
    const short* xs = xb[tt & 1];
#pragma unroll
    for (int ks = 0; ks < 3; ++ks) {
      bf16x8 bv[4];
#pragma unroll
      for (int nf = 0; nf < 4; ++nf)
        bv[nf] = *(const bf16x8*)&xs[swzx(64*wc + 16*nf + l15, 32*ks + 8*l4)];
#pragma unroll
      for (int mf = 0; mf < 2; ++mf)
#pragma unroll
        for (int nf = 0; nf < 4; ++nf)
          acc1[mf][nf] = __builtin_amdgcn_mfma_f32_16x16x32_bf16(
              w1f[mf][ks], bv[nf], acc1[mf][nf], 0, 0, 0);
    }
    short* hs = hb[tt & 1];
#pragma unroll
    for (int mf = 0; mf < 2; ++mf)
#pragma unroll
      for (int nf = 0; nf < 4; ++nf) {
        const int col = 64*wc + 16*nf + l15;
        const int row0 = 32*wr + 16*mf + 4*l4;
        uint2 pk;
        pk.x = cvt_pk_bf16(fmaxf(acc1[mf][nf][0], 0.f), fmaxf(acc1[mf][nf][1], 0.f));
        pk.y = cvt_pk_bf16(fmaxf(acc1[mf][nf][2], 0.f), fmaxf(acc1[mf][nf][3], 0.f));
        *(uint2*)&hs[swzh(col, row0)] = pk;
      }
  };
  auto layer2 = [&](int tt) {         // L2 from hb[tt&1] -> acc2
#pragma unroll
    for (int mf = 0; mf < 2; ++mf)
#pragma unroll
      for (int nf = 0; nf < 4; ++nf) acc2[mf][nf] = f32x4{0.f,0.f,0.f,0.f};
    const short* hs = hb[tt & 1];
#pragma unroll
    for (int ks = 0; ks < 4; ++ks) {
      bf16x8 bv[4];
#pragma unroll
      for (int nf = 0; nf < 4; ++nf)
        bv[nf] = *(const bf16x8*)&hs[swzh(64*wc + 16*nf + l15, 32*ks + 8*l4)];
#pragma unroll
      for (int mf = 0; mf < 2; ++mf)
#pragma unroll
        for (int nf = 0; nf < 4; ++nf)
          acc2[mf][nf] = __builtin_amdgcn_mfma_f32_16x16x32_bf16(
              w2f[mf][ks], bv[nf], acc2[mf][nf], 0, 0, 0);
    }
  };

  // ----- prologue -----
  stage(0);
  fill(0, 0);
  stage(1);
  __syncthreads();                 // xb[0] visible
  layer1_h1(0);                    // hb[0]
  fill(1, 1);
  stage(2);
  __syncthreads();                 // hb[0], xb[1] visible

  // ----- main loop: one barrier per tile -----
  for (int it = 0; it < TPB; ++it) {
    const int tile = tile0 + it;
    const int bb = tile >> 8;
    const int pb = (tile & 255) * 4;

    layer2(it);                    // reads hb[it&1]

    // pool + store (wave covers points pb+2*wc and pb+2*wc+1)
#pragma unroll
    for (int mf = 0; mf < 2; ++mf)
#pragma unroll
      for (int r = 0; r < 4; ++r) {
        float v0 = fmaxf(acc2[mf][0][r], acc2[mf][1][r]);
        float v1 = fmaxf(acc2[mf][2][r], acc2[mf][3][r]);
        v0 = dpp_max16(v0);
        v1 = dpp_max16(v1);
        v0 = fmaxf(v0 + bias2[mf][r], 0.f);
        v1 = fmaxf(v1 + bias2[mf][r], 0.f);
        if (l15 == 0) {
          const int row = 32*wr + 16*mf + 4*l4 + r;
          *(float2*)&out[(size_t)(bb*131 + 3 + row)*NP + pb + 2*wc] = float2{v0, v1};
        }
      }

    if (it + 1 < TPB) layer1_h1(it + 1);   // xb[(it+1)&1] -> hb[(it+1)&1]
    if (it + 2 < TPB) fill(it + 2, it & 1);
    if (it + 3 < TPB) stage(it + 3);
    if (it + 1 < TPB) __syncthreads();
  }
}

extern "C" void kernel_launch(void* const* d_in, const int* in_sizes, int n_in,
                              void* d_out, int out_size, void* d_ws, size_t ws_size,
                              hipStream_t stream) {
  const float* inp    = (const float*)d_in[0];
  const float* normal = (const float*)d_in[1];
  const float* w1     = (const float*)d_in[2];
  const float* b1     = (const float*)d_in[3];
  const float* w2     = (const float*)d_in[4];
  const float* b2     = (const float*)d_in[5];
  float* out = (float*)d_out;

  mlp_kernel<<<dim3(NB*NP/4/TPB), dim3(512), 0, stream>>>(
      inp, w1, b1, w2, b2, normal, out);
}